// Round 7
// baseline (85.373 us; speedup 1.0000x reference)
//
#include <hip/hip_runtime.h>
#include <math.h>

#define DIM 512
#define NROWS 50000
#define NORM 0.04419417382415922f   // 1/sqrt(512)

#define QPART_BLOCKS 32             // 16 rows of W_query each
#define V_BLOCKS 128                // 4 rows of W_key each (wave-per-row)
#define CP_BLOCKS 2048              // 8192 waves
#define CP_THREADS 256
#define GROUPS 64                   // CP_BLOCKS / 32 counter groups
#define KMAX 7                      // ceil(NROWS / 8192 waves)

// out layout (floats): [0,512) q_max | [512] attn_max | [513] log_attn_max
//                      | [514,1026) concat | [1026,51026) maskf | [51026] max_indx
#define OUT_ATTN 512
#define OUT_LOG  513
#define OUT_IDX  51026
// Final 128B line of out = floats [51008,51040): maskf i>=49982 + OUT_IDX.
// Single-writer rule (proven R5): only the winner block touches that line.
#define MASKF_SPLIT 49982

// ws layout (floats):
// [0,16384) qpart (32x512) | [16384,16896) v | [16896,18944) pm
// [18944,20992) ps | [20992,23040) pidx(int) | [23040,23105) counters(uint)

__device__ inline float dot4(float4 a, float4 b, float acc) {
    acc = fmaf(a.x, b.x, acc);
    acc = fmaf(a.y, b.y, acc);
    acc = fmaf(a.z, b.z, acc);
    acc = fmaf(a.w, b.w, acc);
    return acc;
}

__device__ inline float tanh10(float x) {
    // 10*tanh(x) = 10 - 20/(exp2(2x*log2e)+1); exact enough (R6: absmax 0)
    float u = __builtin_amdgcn_exp2f(x * 2.885390081777927f);
    return fmaf(-20.f, __builtin_amdgcn_rcpf(u + 1.f), 10.f);
}

// online-softmax + first-occurrence argmax combine (associative)
__device__ inline void sm_combine(float& m, float& s, int& idx,
                                  float m2, float s2, int idx2) {
    bool take2 = (m2 > m) || (m2 == m && idx2 < idx);
    float hm = take2 ? m2 : m;
    float hs = take2 ? s2 : s;
    int   hi = take2 ? idx2 : idx;
    float lm = take2 ? m : m2;
    float ls = take2 ? s : s2;
    if (lm > -INFINITY) hs = fmaf(ls, __expf(lm - hm), hs);
    m = hm; s = hs; idx = hi;
}

// Stage 1: concat, g_context, split-K partials of Q; zero counters.
__global__ __launch_bounds__(256) void qpart_kernel(
    const float* __restrict__ l, const float* __restrict__ ctx,
    const float* __restrict__ g, const float* __restrict__ Wc,
    const float* __restrict__ Wg, const float* __restrict__ Wq,
    float* __restrict__ qpart, float* __restrict__ out_concat,
    unsigned* __restrict__ counters) {
    int t = threadIdx.x;
    int b = blockIdx.x;
    if (b == 0 && t < GROUPS + 1) counters[t] = 0u;

    __shared__ float gctx[DIM];
    float wc0 = Wc[0], wc1 = Wc[1], wg0 = Wg[0], wg1 = Wg[1];
    for (int j = t; j < DIM; j += 256) {
        float cc = wc0 * l[j] + wc1 * ctx[j];
        if (b == 0) out_concat[j] = cc;
        gctx[j] = wg0 * g[j] + wg1 * cc;
    }
    __syncthreads();
    int d0 = b * 16;
    float acc0 = 0.f, acc1 = 0.f;
    #pragma unroll
    for (int d = 0; d < 16; ++d) {
        float gd = gctx[d0 + d];
        acc0 = fmaf(gd, Wq[(d0 + d) * DIM + t], acc0);
        acc1 = fmaf(gd, Wq[(d0 + d) * DIM + t + 256], acc1);
    }
    qpart[b * DIM + t] = acc0;
    qpart[b * DIM + t + 256] = acc1;
}

// Stage 2: reduce Q partials (fixed order) then v[r] = W_key[r,:] . Q
__global__ __launch_bounds__(256) void v_kernel(
    const float* __restrict__ Wk, const float* __restrict__ qpart,
    float* __restrict__ v) {
    __shared__ __align__(16) float Q[DIM];
    int t = threadIdx.x;
    for (int j = t; j < DIM; j += 256) {
        float a = 0.f;
        for (int p = 0; p < QPART_BLOCKS; ++p) a += qpart[p * DIM + j];
        Q[j] = a;
    }
    __syncthreads();
    int lane = t & 63;
    int w = t >> 6;
    int r = blockIdx.x * 4 + w;
    const float4* row = (const float4*)(Wk + (size_t)r * DIM);
    const float4* qv = (const float4*)Q;
    float4 a0 = row[lane],      a1 = row[lane + 64];
    float4 b0 = qv[lane],       b1 = qv[lane + 64];
    float d = dot4(a1, b1, dot4(a0, b0, 0.f));
    #pragma unroll
    for (int off = 32; off > 0; off >>= 1) d += __shfl_xor(d, off);
    if (lane == 0) v[r] = d;
}

// Stage 3: compat dots + online-softmax partials + maskf copy,
// then last-block (two-level counter) finalize. No compat array stored.
__global__ __launch_bounds__(CP_THREADS) void compat_kernel(
    const float* __restrict__ q, const int* __restrict__ mask,
    const float* __restrict__ v,
    float* __restrict__ pm, float* __restrict__ ps, int* __restrict__ pidx,
    unsigned* __restrict__ counters, const int* __restrict__ is_random,
    const long long* __restrict__ rnet, float* __restrict__ out) {
    int t = threadIdx.x;
    int gtid = blockIdx.x * CP_THREADS + t;
    float* out_maskf = out + 1026;
    if (gtid < MASKF_SPLIT) out_maskf[gtid] = (float)mask[gtid];

    int lane = t & 63;
    int w = t >> 6;
    int wid = gtid >> 6;
    const int nw = (CP_BLOCKS * CP_THREADS) >> 6;   // 8192 waves

    const float4* vv = (const float4*)v;
    float4 vb0 = vv[lane];
    float4 vb1 = vv[lane + 64];

    // preload all masks for this wave's rows (independent scalar loads)
    int mk[KMAX];
    #pragma unroll
    for (int k = 0; k < KMAX; ++k) {
        int n = wid + k * nw;
        mk[k] = (n < NROWS) ? mask[n] : 0;
    }

    float m = -INFINITY, s = 0.f;
    int idx = 0x7fffffff;
    #pragma unroll
    for (int k = 0; k < KMAX; ++k) {
        int n = wid + k * nw;
        if (mk[k]) {
            const float4* row = (const float4*)(q + (size_t)n * DIM);
            float4 a0 = row[lane];
            float4 a1 = row[lane + 64];
            float d = dot4(a1, vb1, dot4(a0, vb0, 0.f));
            #pragma unroll
            for (int off = 32; off > 0; off >>= 1) d += __shfl_xor(d, off);
            float c = tanh10(NORM * d);
            sm_combine(m, s, idx, c, 1.0f, n);
        }
    }

    __shared__ float bm[CP_THREADS / 64], bs[CP_THREADS / 64];
    __shared__ int bidx[CP_THREADS / 64];
    if (lane == 0) { bm[w] = m; bs[w] = s; bidx[w] = idx; }
    __syncthreads();

    __shared__ unsigned isWinner;
    if (t == 0) {
        float M = bm[0], S = bs[0];
        int I = bidx[0];
        for (int i = 1; i < CP_THREADS / 64; ++i)
            sm_combine(M, S, I, bm[i], bs[i], bidx[i]);
        pm[blockIdx.x] = M;
        ps[blockIdx.x] = S;
        pidx[blockIdx.x] = I;
        __threadfence();                          // release partials
        unsigned win = 0;
        unsigned p1 = atomicAdd(&counters[blockIdx.x >> 5], 1u);
        if (p1 == 31u) {                          // last of 32-block group
            __threadfence();
            unsigned p2 = atomicAdd(&counters[GROUPS], 1u);
            if (p2 == GROUPS - 1u) win = 1;       // last group overall
        }
        isWinner = win;
    }
    __syncthreads();
    if (!isWinner) return;
    __threadfence();                              // acquire all partials

    // ---- finalize (winner block only) ----
    __shared__ float fm[CP_THREADS], fs[CP_THREADS], fd[CP_THREADS];
    __shared__ int fi[CP_THREADS];
    float M = -INFINITY, S = 0.f;
    int I = 0x7fffffff;
    for (int i = t; i < CP_BLOCKS; i += CP_THREADS)
        sm_combine(M, S, I, pm[i], ps[i], pidx[i]);
    fm[t] = M; fs[t] = S; fi[t] = I;
    __syncthreads();
    for (int off = CP_THREADS / 2; off > 0; off >>= 1) {
        if (t < off) {
            float M2 = fm[t], S2 = fs[t];
            int I2 = fi[t];
            sm_combine(M2, S2, I2, fm[t + off], fs[t + off], fi[t + off]);
            fm[t] = M2; fs[t] = S2; fi[t] = I2;
        }
        __syncthreads();
    }
    __shared__ int chosenIx, chosenRnd;
    __shared__ float chosenM, chosenS;
    if (t == 0) {
        chosenRnd = is_random[0];
        chosenIx = chosenRnd ? (int)rnet[0] : fi[0];
        chosenM = fm[0];
        chosenS = fs[0];
    }
    __syncthreads();
    int ix = chosenIx;
    float r0 = q[(size_t)ix * DIM + t];
    float r1 = q[(size_t)ix * DIM + t + 256];
    out[t] = r0;
    out[t + 256] = r1;
    // single-writer tail line: maskf[49982..50000) + OUT_IDX
    if (t < NROWS - MASKF_SPLIT)
        out_maskf[MASKF_SPLIT + t] = (float)mask[MASKF_SPLIT + t];
    // dot for random-path compat recompute (fixed-order tree)
    fd[t] = fmaf(r0, v[t], r1 * v[t + 256]);
    __syncthreads();
    for (int off = CP_THREADS / 2; off > 0; off >>= 1) {
        if (t < off) fd[t] += fd[t + off];
        __syncthreads();
    }
    if (t == 0) {
        float Mv = chosenM, Sv = chosenS;
        float c = chosenRnd
                ? (mask[ix] ? tanh10(NORM * fd[0]) : -INFINITY)
                : Mv;                              // argmax row: compat == M
        __hip_atomic_store(&out[OUT_ATTN], expf(c - Mv) / Sv,
                           __ATOMIC_RELAXED, __HIP_MEMORY_SCOPE_AGENT);
        __hip_atomic_store(&out[OUT_LOG], (c - Mv) - logf(Sv),
                           __ATOMIC_RELAXED, __HIP_MEMORY_SCOPE_AGENT);
        __hip_atomic_store(&out[OUT_IDX], (float)ix,
                           __ATOMIC_RELAXED, __HIP_MEMORY_SCOPE_AGENT);
    }
}

extern "C" void kernel_launch(void* const* d_in, const int* in_sizes, int n_in,
                              void* d_out, int out_size, void* d_ws, size_t ws_size,
                              hipStream_t stream) {
    const float*     q    = (const float*)d_in[0];
    const float*     l    = (const float*)d_in[1];
    const float*     ctx  = (const float*)d_in[2];
    const float*     g    = (const float*)d_in[3];
    const int*       mask = (const int*)d_in[4];
    const int*       isr  = (const int*)d_in[5];
    const long long* rnet = (const long long*)d_in[6];
    const float*     Wc   = (const float*)d_in[7];
    const float*     Wg   = (const float*)d_in[8];
    const float*     Wq   = (const float*)d_in[9];
    const float*     Wk   = (const float*)d_in[10];

    float* out = (float*)d_out;
    float* ws  = (float*)d_ws;
    float*    qpart    = ws;
    float*    v        = ws + 16384;
    float*    pm       = ws + 16896;
    float*    ps       = ws + 18944;
    int*      pidx     = (int*)(ws + 20992);
    unsigned* counters = (unsigned*)(ws + 23040);

    qpart_kernel<<<QPART_BLOCKS, 256, 0, stream>>>(l, ctx, g, Wc, Wg, Wq,
                                                   qpart, out + 514, counters);
    v_kernel<<<V_BLOCKS, 256, 0, stream>>>(Wk, qpart, v);
    compat_kernel<<<CP_BLOCKS, CP_THREADS, 0, stream>>>(q, mask, v, pm, ps,
                                                        pidx, counters, isr,
                                                        rnet, out);
}

// Round 8
// 48.392 us; speedup vs baseline: 1.7642x; 1.7642x over previous
//
#include <hip/hip_runtime.h>
#include <math.h>

#define DIM 512
#define NROWS 50000
#define NORM 0.04419417382415922f   // 1/sqrt(512)

#define QV_BLOCKS 64                // each computes full Q redundantly + 8 v-rows
#define CP_BLOCKS 2048              // 8192 waves
#define CP_THREADS 256

// out layout (floats): [0,512) q_max | [512] attn_max | [513] log_attn_max
//                      | [514,1026) concat | [1026,51026) maskf | [51026] max_indx
#define OUT_ATTN 512
#define OUT_LOG  513
#define OUT_IDX  51026

// ws layout (floats): [0,512) v | [512,2560) pm | [2560,4608) ps
//                     | [4608,6656) pidx(int)

__device__ inline float dot4(float4 a, float4 b, float acc) {
    acc = fmaf(a.x, b.x, acc);
    acc = fmaf(a.y, b.y, acc);
    acc = fmaf(a.z, b.z, acc);
    acc = fmaf(a.w, b.w, acc);
    return acc;
}

__device__ inline float tanh10(float x) {
    // 10*tanh(x) = 10 - 20/(exp2(2x*log2e)+1); |x|<~1.5 here (validated R6/R7)
    float u = __builtin_amdgcn_exp2f(x * 2.885390081777927f);
    return fmaf(-20.f, __builtin_amdgcn_rcpf(u + 1.f), 10.f);
}

// online-softmax + first-occurrence argmax combine (associative)
__device__ inline void sm_combine(float& m, float& s, int& idx,
                                  float m2, float s2, int idx2) {
    bool take2 = (m2 > m) || (m2 == m && idx2 < idx);
    float hm = take2 ? m2 : m;
    float hs = take2 ? s2 : s;
    int   hi = take2 ? idx2 : idx;
    float lm = take2 ? m : m2;
    float ls = take2 ? s : s2;
    if (lm > -INFINITY) hs = fmaf(ls, __expf(lm - hm), hs);
    m = hm; s = hs; idx = hi;
}

// Stage 1 (fused): concat, g_context, FULL Q per block (redundant,
// deterministic), then 8 rows of v = W_key @ Q per block.
__global__ __launch_bounds__(256) void qv_kernel(
    const float* __restrict__ l, const float* __restrict__ ctx,
    const float* __restrict__ g, const float* __restrict__ Wc,
    const float* __restrict__ Wg, const float* __restrict__ Wq,
    const float* __restrict__ Wk,
    float* __restrict__ v, float* __restrict__ out_concat) {
    int t = threadIdx.x;
    int b = blockIdx.x;
    __shared__ float gctx[DIM];
    __shared__ __align__(16) float Qs[DIM];

    float wc0 = Wc[0], wc1 = Wc[1], wg0 = Wg[0], wg1 = Wg[1];
    for (int j = t; j < DIM; j += 256) {
        float cc = wc0 * l[j] + wc1 * ctx[j];
        if (b == 0) out_concat[j] = cc;
        gctx[j] = wg0 * g[j] + wg1 * cc;
    }
    __syncthreads();

    // Q[2t], Q[2t+1]: two half-K chains (fixed order -> deterministic)
    const float2* Wq2 = (const float2*)Wq;
    float2 acc0 = make_float2(0.f, 0.f), acc1 = make_float2(0.f, 0.f);
    for (int k = 0; k < 256; ++k) {
        float g0 = gctx[k], g1 = gctx[k + 256];
        float2 w0 = Wq2[k * 256 + t];
        float2 w1 = Wq2[(k + 256) * 256 + t];
        acc0.x = fmaf(g0, w0.x, acc0.x);
        acc0.y = fmaf(g0, w0.y, acc0.y);
        acc1.x = fmaf(g1, w1.x, acc1.x);
        acc1.y = fmaf(g1, w1.y, acc1.y);
    }
    ((float2*)Qs)[t] = make_float2(acc0.x + acc1.x, acc0.y + acc1.y);
    __syncthreads();

    int lane = t & 63;
    int w = t >> 6;
    const float4* qv4 = (const float4*)Qs;
    float4 q0 = qv4[lane], q1 = qv4[lane + 64];
    #pragma unroll
    for (int rr = 0; rr < 2; ++rr) {
        int r = b * 8 + w * 2 + rr;
        const float4* row = (const float4*)(Wk + (size_t)r * DIM);
        float4 a0 = row[lane], a1 = row[lane + 64];
        float d = dot4(a1, q1, dot4(a0, q0, 0.f));
        #pragma unroll
        for (int off = 32; off > 0; off >>= 1) d += __shfl_xor(d, off);
        if (lane == 0) v[r] = d;
    }
}

// Stage 2: compat dots (wave-per-row, masked rows skipped entirely),
// per-block online-softmax partial, maskf copy. No compat array stored.
__global__ __launch_bounds__(CP_THREADS) void compat_kernel(
    const float* __restrict__ q, const int* __restrict__ mask,
    const float* __restrict__ v,
    float* __restrict__ pm, float* __restrict__ ps, int* __restrict__ pidx,
    float* __restrict__ out_maskf) {
    int t = threadIdx.x;
    int gtid = blockIdx.x * CP_THREADS + t;
    if (gtid < NROWS) out_maskf[gtid] = (float)mask[gtid];

    int lane = t & 63;
    int w = t >> 6;
    int wid = gtid >> 6;
    const int nw = (CP_BLOCKS * CP_THREADS) >> 6;   // 8192 waves

    const float4* vv = (const float4*)v;
    float4 vb0 = vv[lane];
    float4 vb1 = vv[lane + 64];

    float m = -INFINITY, s = 0.f;
    int idx = 0x7fffffff;

    for (int n = wid; n < NROWS; n += nw) {
        if (mask[n] == 0) continue;          // wave-uniform, skip 2KB read
        const float4* row = (const float4*)(q + (size_t)n * DIM);
        float4 a0 = row[lane];
        float4 a1 = row[lane + 64];
        float d = dot4(a1, vb1, dot4(a0, vb0, 0.f));
        #pragma unroll
        for (int off = 32; off > 0; off >>= 1) d += __shfl_xor(d, off);
        float c = tanh10(NORM * d);
        sm_combine(m, s, idx, c, 1.0f, n);
    }

    __shared__ float bm[CP_THREADS / 64], bs[CP_THREADS / 64];
    __shared__ int bidx[CP_THREADS / 64];
    if (lane == 0) { bm[w] = m; bs[w] = s; bidx[w] = idx; }
    __syncthreads();
    if (t == 0) {
        float M = bm[0], S = bs[0];
        int I = bidx[0];
        for (int i = 1; i < CP_THREADS / 64; ++i)
            sm_combine(M, S, I, bm[i], bs[i], bidx[i]);
        pm[blockIdx.x] = M;
        ps[blockIdx.x] = S;
        pidx[blockIdx.x] = I;
    }
}

// Stage 3: combine partials; attn/log_attn/idx; q_max copy.
// Random path recomputes its compat value from q[ix].v (R7-validated math).
__global__ __launch_bounds__(512) void finalize_kernel(
    const float* __restrict__ q, const int* __restrict__ mask,
    const float* __restrict__ v, const float* __restrict__ pm,
    const float* __restrict__ ps, const int* __restrict__ pidx,
    const int* __restrict__ is_random, const long long* __restrict__ rnet,
    float* __restrict__ out) {
    __shared__ float sm[512], ss[512], sd[512];
    __shared__ int si[512];
    int t = threadIdx.x;
    float m = -INFINITY, s = 0.f;
    int idx = 0x7fffffff;
    for (int i = t; i < CP_BLOCKS; i += 512)
        sm_combine(m, s, idx, pm[i], ps[i], pidx[i]);
    sm[t] = m; ss[t] = s; si[t] = idx;
    __syncthreads();
    for (int off = 256; off > 0; off >>= 1) {
        if (t < off) {
            float M = sm[t], S = ss[t];
            int I = si[t];
            sm_combine(M, S, I, sm[t + off], ss[t + off], si[t + off]);
            sm[t] = M; ss[t] = S; si[t] = I;
        }
        __syncthreads();
    }
    __shared__ int chosenIx, chosenRnd;
    __shared__ float chosenM, chosenS;
    if (t == 0) {
        chosenRnd = is_random[0];
        chosenIx = chosenRnd ? (int)rnet[0] : si[0];
        chosenM = sm[0];
        chosenS = ss[0];
    }
    __syncthreads();
    int ix = chosenIx;
    float r0 = q[(size_t)ix * DIM + t];
    out[t] = r0;
    sd[t] = r0 * v[t];
    __syncthreads();
    for (int off = 256; off > 0; off >>= 1) {
        if (t < off) sd[t] += sd[t + off];
        __syncthreads();
    }
    if (t == 0) {
        float Mv = chosenM, Sv = chosenS;
        float c = chosenRnd
                ? (mask[ix] ? tanh10(NORM * sd[0]) : -INFINITY)
                : Mv;                       // argmax row: compat == M exactly
        out[OUT_ATTN] = __expf(c - Mv) / Sv;
        out[OUT_LOG]  = (c - Mv) - logf(Sv);
        out[OUT_IDX]  = (float)ix;
    }
}

extern "C" void kernel_launch(void* const* d_in, const int* in_sizes, int n_in,
                              void* d_out, int out_size, void* d_ws, size_t ws_size,
                              hipStream_t stream) {
    const float*     q    = (const float*)d_in[0];
    const float*     l    = (const float*)d_in[1];
    const float*     ctx  = (const float*)d_in[2];
    const float*     g    = (const float*)d_in[3];
    const int*       mask = (const int*)d_in[4];
    const int*       isr  = (const int*)d_in[5];
    const long long* rnet = (const long long*)d_in[6];
    const float*     Wc   = (const float*)d_in[7];
    const float*     Wg   = (const float*)d_in[8];
    const float*     Wq   = (const float*)d_in[9];
    const float*     Wk   = (const float*)d_in[10];

    float* out = (float*)d_out;
    float* ws  = (float*)d_ws;
    float* v    = ws;
    float* pm   = ws + 512;
    float* ps   = ws + 2560;
    int*   pidx = (int*)(ws + 4608);

    qv_kernel<<<QV_BLOCKS, 256, 0, stream>>>(l, ctx, g, Wc, Wg, Wq, Wk,
                                             v, out + 514);
    compat_kernel<<<CP_BLOCKS, CP_THREADS, 0, stream>>>(q, mask, v, pm, ps,
                                                        pidx, out + 1026);
    finalize_kernel<<<1, 512, 0, stream>>>(q, mask, v, pm, ps, pidx,
                                           isr, rnet, out);
}

// Round 9
// 33.473 us; speedup vs baseline: 2.5505x; 1.4457x over previous
//
#include <hip/hip_runtime.h>
#include <math.h>

#define DIM 512
#define NROWS 50000
#define NORM 0.04419417382415922f   // 1/sqrt(512)

#define QV_BLOCKS 64                // 8 v-rows each; Q split-K within block
#define QV_THREADS 1024
#define CP_BLOCKS 2048              // 8192 waves
#define CP_THREADS 256

// out layout (floats): [0,512) q_max | [512] attn_max | [513] log_attn_max
//                      | [514,1026) concat | [1026,51026) maskf | [51026] max_indx
#define OUT_ATTN 512
#define OUT_LOG  513
#define OUT_IDX  51026

// ws layout (floats): [0,512) v | [512,2560) pm | [2560,4608) ps
//                     | [4608,6656) pidx(int)

__device__ inline float dot4(float4 a, float4 b, float acc) {
    acc = fmaf(a.x, b.x, acc);
    acc = fmaf(a.y, b.y, acc);
    acc = fmaf(a.z, b.z, acc);
    acc = fmaf(a.w, b.w, acc);
    return acc;
}

__device__ inline float tanh10(float x) {
    // 10*tanh(x) = 10 - 20/(exp2(2x*log2e)+1); |x|<~1.5 here (validated R6-R8)
    float u = __builtin_amdgcn_exp2f(x * 2.885390081777927f);
    return fmaf(-20.f, __builtin_amdgcn_rcpf(u + 1.f), 10.f);
}

// online-softmax + first-occurrence argmax combine (associative)
__device__ inline void sm_combine(float& m, float& s, int& idx,
                                  float m2, float s2, int idx2) {
    bool take2 = (m2 > m) || (m2 == m && idx2 < idx);
    float hm = take2 ? m2 : m;
    float hs = take2 ? s2 : s;
    int   hi = take2 ? idx2 : idx;
    float lm = take2 ? m : m2;
    float ls = take2 ? s : s2;
    if (lm > -INFINITY) hs = fmaf(ls, __expf(lm - hm), hs);
    m = hm; s = hs; idx = hi;
}

// Stage 1 (fused, latency-fixed): concat + g_context + block-local split-K Q
// (1024 threads: thread owns j=t&511, K-half h=t>>9; coalesced Wq walk)
// + 8 rows of v = W_key @ Q per block (2 waves per row).
__global__ __launch_bounds__(QV_THREADS) void qv_kernel(
    const float* __restrict__ l, const float* __restrict__ ctx,
    const float* __restrict__ g, const float* __restrict__ Wc,
    const float* __restrict__ Wg, const float* __restrict__ Wq,
    const float* __restrict__ Wk,
    float* __restrict__ v, float* __restrict__ out_concat) {
    int t = threadIdx.x;
    int b = blockIdx.x;
    __shared__ float gctx[DIM];
    __shared__ __align__(16) float Qs[DIM];
    __shared__ float part[DIM];
    __shared__ float vhalf[16];

    if (t < DIM) {
        float cc = Wc[0] * l[t] + Wc[1] * ctx[t];
        if (b == 0) out_concat[t] = cc;
        gctx[t] = Wg[0] * g[t] + Wg[1] * cc;
    }
    __syncthreads();

    // Q[j] = sum_d gctx[d] * Wq[d*512 + j], split over two 256-d halves
    int j = t & 511;
    int h = t >> 9;
    const float* wq = Wq + (size_t)h * 256 * DIM + j;
    const float* gc = gctx + h * 256;
    float acc = 0.f;
    #pragma unroll 16
    for (int d = 0; d < 256; ++d)
        acc = fmaf(gc[d], wq[(size_t)d * DIM], acc);
    if (h) part[j] = acc;
    __syncthreads();
    if (!h) Qs[j] = acc + part[j];
    __syncthreads();

    // v rows: wave w (0..15) handles row r = b*8 + w/2, half = w&1
    int w = t >> 6, lane = t & 63;
    int r = b * 8 + (w >> 1);
    int half = w & 1;
    const float4* row4 = (const float4*)(Wk + (size_t)r * DIM) + half * 64;
    const float4* q4 = (const float4*)Qs + half * 64;
    float d = dot4(row4[lane], q4[lane], 0.f);
    #pragma unroll
    for (int off = 32; off > 0; off >>= 1) d += __shfl_xor(d, off);
    if (lane == 0) vhalf[w] = d;
    __syncthreads();
    if (t < 8) v[b * 8 + t] = vhalf[2 * t] + vhalf[2 * t + 1];
}

// Stage 2: compat dots (wave-per-row, masked rows skipped entirely),
// per-block online-softmax partial, maskf copy. No compat array stored.
__global__ __launch_bounds__(CP_THREADS) void compat_kernel(
    const float* __restrict__ q, const int* __restrict__ mask,
    const float* __restrict__ v,
    float* __restrict__ pm, float* __restrict__ ps, int* __restrict__ pidx,
    float* __restrict__ out_maskf) {
    int t = threadIdx.x;
    int gtid = blockIdx.x * CP_THREADS + t;
    if (gtid < NROWS) out_maskf[gtid] = (float)mask[gtid];

    int lane = t & 63;
    int w = t >> 6;
    int wid = gtid >> 6;
    const int nw = (CP_BLOCKS * CP_THREADS) >> 6;   // 8192 waves

    const float4* vv = (const float4*)v;
    float4 vb0 = vv[lane];
    float4 vb1 = vv[lane + 64];

    float m = -INFINITY, s = 0.f;
    int idx = 0x7fffffff;

    for (int n = wid; n < NROWS; n += nw) {
        if (mask[n] == 0) continue;          // wave-uniform, skip 2KB read
        const float4* row = (const float4*)(q + (size_t)n * DIM);
        float4 a0 = row[lane];
        float4 a1 = row[lane + 64];
        float d = dot4(a1, vb1, dot4(a0, vb0, 0.f));
        #pragma unroll
        for (int off = 32; off > 0; off >>= 1) d += __shfl_xor(d, off);
        float c = tanh10(NORM * d);
        sm_combine(m, s, idx, c, 1.0f, n);
    }

    __shared__ float bm[CP_THREADS / 64], bs[CP_THREADS / 64];
    __shared__ int bidx[CP_THREADS / 64];
    if (lane == 0) { bm[w] = m; bs[w] = s; bidx[w] = idx; }
    __syncthreads();
    if (t == 0) {
        float M = bm[0], S = bs[0];
        int I = bidx[0];
        for (int i = 1; i < CP_THREADS / 64; ++i)
            sm_combine(M, S, I, bm[i], bs[i], bidx[i]);
        pm[blockIdx.x] = M;
        ps[blockIdx.x] = S;
        pidx[blockIdx.x] = I;
    }
}

// Stage 3: combine partials; attn/log_attn/idx; q_max copy.
// Random path recomputes its compat value from q[ix].v (validated R7/R8).
__global__ __launch_bounds__(512) void finalize_kernel(
    const float* __restrict__ q, const int* __restrict__ mask,
    const float* __restrict__ v, const float* __restrict__ pm,
    const float* __restrict__ ps, const int* __restrict__ pidx,
    const int* __restrict__ is_random, const long long* __restrict__ rnet,
    float* __restrict__ out) {
    __shared__ float sm[512], ss[512], sd[512];
    __shared__ int si[512];
    int t = threadIdx.x;
    float m = -INFINITY, s = 0.f;
    int idx = 0x7fffffff;
    for (int i = t; i < CP_BLOCKS; i += 512)
        sm_combine(m, s, idx, pm[i], ps[i], pidx[i]);
    sm[t] = m; ss[t] = s; si[t] = idx;
    __syncthreads();
    for (int off = 256; off > 0; off >>= 1) {
        if (t < off) {
            float M = sm[t], S = ss[t];
            int I = si[t];
            sm_combine(M, S, I, sm[t + off], ss[t + off], si[t + off]);
            sm[t] = M; ss[t] = S; si[t] = I;
        }
        __syncthreads();
    }
    __shared__ int chosenIx, chosenRnd;
    __shared__ float chosenM, chosenS;
    if (t == 0) {
        chosenRnd = is_random[0];
        chosenIx = chosenRnd ? (int)rnet[0] : si[0];
        chosenM = sm[0];
        chosenS = ss[0];
    }
    __syncthreads();
    int ix = chosenIx;
    float r0 = q[(size_t)ix * DIM + t];
    out[t] = r0;
    sd[t] = r0 * v[t];
    __syncthreads();
    for (int off = 256; off > 0; off >>= 1) {
        if (t < off) sd[t] += sd[t + off];
        __syncthreads();
    }
    if (t == 0) {
        float Mv = chosenM, Sv = chosenS;
        float c = chosenRnd
                ? (mask[ix] ? tanh10(NORM * sd[0]) : -INFINITY)
                : Mv;                       // argmax row: compat == M exactly
        out[OUT_ATTN] = __expf(c - Mv) / Sv;
        out[OUT_LOG]  = (c - Mv) - logf(Sv);
        out[OUT_IDX]  = (float)ix;
    }
}

extern "C" void kernel_launch(void* const* d_in, const int* in_sizes, int n_in,
                              void* d_out, int out_size, void* d_ws, size_t ws_size,
                              hipStream_t stream) {
    const float*     q    = (const float*)d_in[0];
    const float*     l    = (const float*)d_in[1];
    const float*     ctx  = (const float*)d_in[2];
    const float*     g    = (const float*)d_in[3];
    const int*       mask = (const int*)d_in[4];
    const int*       isr  = (const int*)d_in[5];
    const long long* rnet = (const long long*)d_in[6];
    const float*     Wc   = (const float*)d_in[7];
    const float*     Wg   = (const float*)d_in[8];
    const float*     Wq   = (const float*)d_in[9];
    const float*     Wk   = (const float*)d_in[10];

    float* out = (float*)d_out;
    float* ws  = (float*)d_ws;
    float* v    = ws;
    float* pm   = ws + 512;
    float* ps   = ws + 2560;
    int*   pidx = (int*)(ws + 4608);

    qv_kernel<<<QV_BLOCKS, QV_THREADS, 0, stream>>>(l, ctx, g, Wc, Wg, Wq, Wk,
                                                    v, out + 514);
    compat_kernel<<<CP_BLOCKS, CP_THREADS, 0, stream>>>(q, mask, v, pm, ps,
                                                        pidx, out + 1026);
    finalize_kernel<<<1, 512, 0, stream>>>(q, mask, v, pm, ps, pidx,
                                           isr, rnet, out);
}

// Round 10
// 31.632 us; speedup vs baseline: 2.6989x; 1.0582x over previous
//
#include <hip/hip_runtime.h>
#include <math.h>

#define DIM 512
#define NROWS 50000
#define NORM 0.04419417382415922f   // 1/sqrt(512)

#define QV_BLOCKS 8                 // split-N: 64 output-cols each, exact
#define JS 64                       // j-slice width per block
#define CP_BLOCKS 512
#define CP_THREADS 1024             // 512x1024 = 8192 waves total
#define NWAVES 8192

// out layout (floats): [0,512) q_max | [512] attn_max | [513] log_attn_max
//                      | [514,1026) concat | [1026,51026) maskf | [51026] max_indx
#define OUT_ATTN 512
#define OUT_LOG  513
#define OUT_IDX  51026

// ws layout (floats): [0,4096) vpart (8x512) | [4096,4608) pm
//                     | [4608,5120) ps | [5120,5632) pidx(int)

__device__ inline float dot4(float4 a, float4 b, float acc) {
    acc = fmaf(a.x, b.x, acc);
    acc = fmaf(a.y, b.y, acc);
    acc = fmaf(a.z, b.z, acc);
    acc = fmaf(a.w, b.w, acc);
    return acc;
}

__device__ inline float tanh10(float x) {
    // 10*tanh(x) = 10 - 20/(exp2(2x*log2e)+1); |x|<~1.5 here (validated R6-R9)
    float u = __builtin_amdgcn_exp2f(x * 2.885390081777927f);
    return fmaf(-20.f, __builtin_amdgcn_rcpf(u + 1.f), 10.f);
}

// online-softmax + first-occurrence argmax combine (associative)
__device__ inline void sm_combine(float& m, float& s, int& idx,
                                  float m2, float s2, int idx2) {
    bool take2 = (m2 > m) || (m2 == m && idx2 < idx);
    float hm = take2 ? m2 : m;
    float hs = take2 ? s2 : s;
    int   hi = take2 ? idx2 : idx;
    float lm = take2 ? m : m2;
    float ls = take2 ? s : s2;
    if (lm > -INFINITY) hs = fmaf(ls, __expf(lm - hm), hs);
    m = hm; s = hs; idx = hi;
}

// Stage 1 (fused QV, non-redundant split-N): block b owns cols Jb=[b*64,b*64+64).
// Q[Jb] = gctx . Wq[:,Jb]  (exact, no cross-block reduce)
// vpart[b][r] = Wk[r,Jb] . Q[Jb]   for all r  (v = sum_b vpart[b] by linearity)
__global__ __launch_bounds__(256) void qv_kernel(
    const float* __restrict__ l, const float* __restrict__ ctx,
    const float* __restrict__ g, const float* __restrict__ Wc,
    const float* __restrict__ Wg, const float* __restrict__ Wq,
    const float* __restrict__ Wk,
    float* __restrict__ vpart, float* __restrict__ out_concat) {
    int t = threadIdx.x;
    int b = blockIdx.x;
    __shared__ float gctx[DIM];
    __shared__ float qred[256];
    __shared__ __align__(16) float Qs[JS];

    float wc0 = Wc[0], wc1 = Wc[1], wg0 = Wg[0], wg1 = Wg[1];
    for (int j = t; j < DIM; j += 256) {
        float cc = wc0 * l[j] + wc1 * ctx[j];
        if (b == 0) out_concat[j] = cc;
        gctx[j] = wg0 * g[j] + wg1 * cc;
    }
    __syncthreads();

    // Q slice: local col jj = t&63, d-chunk ch = t>>6 (4 chunks x 128 d)
    int jj = t & 63;
    int ch = t >> 6;
    const float* wq = Wq + (size_t)(ch * 128) * DIM + b * JS + jj;
    const float* gc = gctx + ch * 128;
    float acc = 0.f;
    #pragma unroll 16
    for (int d = 0; d < 128; ++d)
        acc = fmaf(gc[d], wq[(size_t)d * DIM], acc);
    qred[t] = acc;
    __syncthreads();
    if (t < JS)
        Qs[t] = (qred[t] + qred[t + 64]) + (qred[t + 128] + qred[t + 192]);
    __syncthreads();

    // vpart rows: thread t handles r = t and r = t+256 (64 cols each, contiguous)
    const float4* q4 = (const float4*)Qs;
    #pragma unroll
    for (int rr = 0; rr < 2; ++rr) {
        int r = t + rr * 256;
        const float4* wk4 = (const float4*)(Wk + (size_t)r * DIM + b * JS);
        float a = 0.f;
        #pragma unroll
        for (int c = 0; c < JS / 4; ++c)
            a = dot4(wk4[c], q4[c], a);
        vpart[b * DIM + r] = a;
    }
}

// Stage 2: reduce vpart -> LDS v, then compat dots (wave-per-row, masked rows
// skipped), per-block online-softmax partial, maskf copy. 512 blocks x 1024.
__global__ __launch_bounds__(CP_THREADS, 8) void compat_kernel(
    const float* __restrict__ q, const int* __restrict__ mask,
    const float* __restrict__ vpart,
    float* __restrict__ pm, float* __restrict__ ps, int* __restrict__ pidx,
    float* __restrict__ out_maskf) {
    int t = threadIdx.x;
    int gtid = blockIdx.x * CP_THREADS + t;
    if (gtid < NROWS) out_maskf[gtid] = (float)mask[gtid];

    __shared__ __align__(16) float vlds[DIM];
    if (t < DIM) {
        float a = 0.f;
        #pragma unroll
        for (int b = 0; b < QV_BLOCKS; ++b) a += vpart[b * DIM + t];
        vlds[t] = a;
    }
    __syncthreads();

    int lane = t & 63;
    int w = t >> 6;                  // 0..15
    int wid = gtid >> 6;
    const float4* vv = (const float4*)vlds;
    float4 vb0 = vv[lane];
    float4 vb1 = vv[lane + 64];

    float m = -INFINITY, s = 0.f;
    int idx = 0x7fffffff;

    for (int n = wid; n < NROWS; n += NWAVES) {
        if (mask[n] == 0) continue;          // wave-uniform, skip 2KB read
        const float4* row = (const float4*)(q + (size_t)n * DIM);
        float4 a0 = row[lane];
        float4 a1 = row[lane + 64];
        float d = dot4(a1, vb1, dot4(a0, vb0, 0.f));
        #pragma unroll
        for (int off = 32; off > 0; off >>= 1) d += __shfl_xor(d, off);
        float c = tanh10(NORM * d);
        sm_combine(m, s, idx, c, 1.0f, n);
    }

    __shared__ float bm[16], bs[16];
    __shared__ int bidx[16];
    if (lane == 0) { bm[w] = m; bs[w] = s; bidx[w] = idx; }
    __syncthreads();
    if (t == 0) {
        float M = bm[0], S = bs[0];
        int I = bidx[0];
        for (int i = 1; i < 16; ++i)
            sm_combine(M, S, I, bm[i], bs[i], bidx[i]);
        pm[blockIdx.x] = M;
        ps[blockIdx.x] = S;
        pidx[blockIdx.x] = I;
    }
}

// Stage 3: combine 512 partials; attn/log_attn/idx; q_max copy.
// Random path recomputes its compat from q[ix].v (v re-reduced from vpart).
__global__ __launch_bounds__(512) void finalize_kernel(
    const float* __restrict__ q, const int* __restrict__ mask,
    const float* __restrict__ vpart, const float* __restrict__ pm,
    const float* __restrict__ ps, const int* __restrict__ pidx,
    const int* __restrict__ is_random, const long long* __restrict__ rnet,
    float* __restrict__ out) {
    __shared__ float sm[512], ss[512], sd[512];
    __shared__ int si[512];
    int t = threadIdx.x;
    float m = pm[t], s = ps[t];
    int idx = pidx[t];
    sm[t] = m; ss[t] = s; si[t] = idx;
    __syncthreads();
    for (int off = 256; off > 0; off >>= 1) {
        if (t < off) {
            float M = sm[t], S = ss[t];
            int I = si[t];
            sm_combine(M, S, I, sm[t + off], ss[t + off], si[t + off]);
            sm[t] = M; ss[t] = S; si[t] = I;
        }
        __syncthreads();
    }
    __shared__ int chosenIx, chosenRnd;
    __shared__ float chosenM, chosenS;
    if (t == 0) {
        chosenRnd = is_random[0];
        chosenIx = chosenRnd ? (int)rnet[0] : si[0];
        chosenM = sm[0];
        chosenS = ss[0];
    }
    __syncthreads();
    int ix = chosenIx;
    float r0 = q[(size_t)ix * DIM + t];
    out[t] = r0;
    float vt = 0.f;
    #pragma unroll
    for (int b = 0; b < QV_BLOCKS; ++b) vt += vpart[b * DIM + t];
    sd[t] = r0 * vt;
    __syncthreads();
    for (int off = 256; off > 0; off >>= 1) {
        if (t < off) sd[t] += sd[t + off];
        __syncthreads();
    }
    if (t == 0) {
        float Mv = chosenM, Sv = chosenS;
        float c = chosenRnd
                ? (mask[ix] ? tanh10(NORM * sd[0]) : -INFINITY)
                : Mv;                       // argmax row: compat == M exactly
        out[OUT_ATTN] = __expf(c - Mv) / Sv;
        out[OUT_LOG]  = (c - Mv) - logf(Sv);
        out[OUT_IDX]  = (float)ix;
    }
}

extern "C" void kernel_launch(void* const* d_in, const int* in_sizes, int n_in,
                              void* d_out, int out_size, void* d_ws, size_t ws_size,
                              hipStream_t stream) {
    const float*     q    = (const float*)d_in[0];
    const float*     l    = (const float*)d_in[1];
    const float*     ctx  = (const float*)d_in[2];
    const float*     g    = (const float*)d_in[3];
    const int*       mask = (const int*)d_in[4];
    const int*       isr  = (const int*)d_in[5];
    const long long* rnet = (const long long*)d_in[6];
    const float*     Wc   = (const float*)d_in[7];
    const float*     Wg   = (const float*)d_in[8];
    const float*     Wq   = (const float*)d_in[9];
    const float*     Wk   = (const float*)d_in[10];

    float* out = (float*)d_out;
    float* ws  = (float*)d_ws;
    float* vpart = ws;
    float* pm    = ws + 4096;
    float* ps    = ws + 4608;
    int*   pidx  = (int*)(ws + 5120);

    qv_kernel<<<QV_BLOCKS, 256, 0, stream>>>(l, ctx, g, Wc, Wg, Wq, Wk,
                                             vpart, out + 514);
    compat_kernel<<<CP_BLOCKS, CP_THREADS, 0, stream>>>(q, mask, vpart, pm, ps,
                                                        pidx, out + 1026);
    finalize_kernel<<<1, 512, 0, stream>>>(q, mask, vpart, pm, ps, pidx,
                                           isr, rnet, out);
}

// Round 11
// 31.187 us; speedup vs baseline: 2.7374x; 1.0143x over previous
//
#include <hip/hip_runtime.h>
#include <math.h>

#define DIM 512
#define NROWS 50000
#define NORM 0.04419417382415922f   // 1/sqrt(512)

#define QP_BLOCKS 64                // 32 compute qpart; all 64 copy maskf
#define QPART_BLOCKS 32             // 16 rows of W_query each
#define VK_BLOCKS 128               // 4 rows of W_key each (wave-per-row)
#define CP_BLOCKS 2048              // 8192 waves = full occupancy
#define CP_THREADS 256
#define KMAX 7                      // ceil(NROWS / 8192 waves)

// out layout (floats): [0,512) q_max | [512] attn_max | [513] log_attn_max
//                      | [514,1026) concat | [1026,51026) maskf | [51026] max_indx
#define OUT_ATTN 512
#define OUT_LOG  513
#define OUT_IDX  51026

// ws layout (floats):
// [0,16384) qpart (32x512) | [16384,16896) v | [16896,18944) pm
// [18944,20992) ps | [20992,23040) pidx(int)

__device__ inline float dot4(float4 a, float4 b, float acc) {
    acc = fmaf(a.x, b.x, acc);
    acc = fmaf(a.y, b.y, acc);
    acc = fmaf(a.z, b.z, acc);
    acc = fmaf(a.w, b.w, acc);
    return acc;
}

__device__ inline float tanh10(float x) {
    // 10*tanh(x) = 10 - 20/(exp2(2x*log2e)+1); |x|<~1.5 here (validated R6-R10)
    float u = __builtin_amdgcn_exp2f(x * 2.885390081777927f);
    return fmaf(-20.f, __builtin_amdgcn_rcpf(u + 1.f), 10.f);
}

// online-softmax + first-occurrence argmax combine (associative)
__device__ inline void sm_combine(float& m, float& s, int& idx,
                                  float m2, float s2, int idx2) {
    bool take2 = (m2 > m) || (m2 == m && idx2 < idx);
    float hm = take2 ? m2 : m;
    float hs = take2 ? s2 : s;
    int   hi = take2 ? idx2 : idx;
    float lm = take2 ? m : m2;
    float ls = take2 ? s : s2;
    if (lm > -INFINITY) hs = fmaf(ls, __expf(lm - hm), hs);
    m = hm; s = hs; idx = hi;
}

// Stage 1: concat, g_context, split-K partials of Q = g_context @ W_query.
// Extra blocks handle the mask -> float copy so compat stays pure. (R3 body)
__global__ __launch_bounds__(256) void qpart_kernel(
    const float* __restrict__ l, const float* __restrict__ ctx,
    const float* __restrict__ g, const float* __restrict__ Wc,
    const float* __restrict__ Wg, const float* __restrict__ Wq,
    const int* __restrict__ mask,
    float* __restrict__ qpart, float* __restrict__ out_concat,
    float* __restrict__ out_maskf) {
    int t = threadIdx.x;
    int b = blockIdx.x;
    for (int i = b * 256 + t; i < NROWS; i += QP_BLOCKS * 256)
        out_maskf[i] = (float)mask[i];
    if (b >= QPART_BLOCKS) return;

    __shared__ float gctx[DIM];
    float wc0 = Wc[0], wc1 = Wc[1], wg0 = Wg[0], wg1 = Wg[1];
    for (int j = t; j < DIM; j += 256) {
        float cc = wc0 * l[j] + wc1 * ctx[j];
        if (b == 0) out_concat[j] = cc;
        gctx[j] = wg0 * g[j] + wg1 * cc;
    }
    __syncthreads();
    int d0 = b * 16;
    float acc0 = 0.f, acc1 = 0.f;
    #pragma unroll
    for (int d = 0; d < 16; ++d) {
        float gd = gctx[d0 + d];
        acc0 = fmaf(gd, Wq[(d0 + d) * DIM + t], acc0);
        acc1 = fmaf(gd, Wq[(d0 + d) * DIM + t + 256], acc1);
    }
    qpart[b * DIM + t] = acc0;
    qpart[b * DIM + t + 256] = acc1;
}

// Stage 2: reduce Q partials (fixed order) then v[r] = W_key[r,:] . Q  (R3 body)
__global__ __launch_bounds__(256) void v_kernel(
    const float* __restrict__ Wk, const float* __restrict__ qpart,
    float* __restrict__ v) {
    __shared__ __align__(16) float Q[DIM];
    int t = threadIdx.x;
    for (int j = t; j < DIM; j += 256) {
        float a = 0.f;
        for (int p = 0; p < QPART_BLOCKS; ++p) a += qpart[p * DIM + j];
        Q[j] = a;
    }
    __syncthreads();
    int lane = t & 63;
    int w = t >> 6;
    int r = blockIdx.x * 4 + w;
    const float4* row = (const float4*)(Wk + (size_t)r * DIM);
    const float4* qv = (const float4*)Q;
    float4 a0 = row[lane],      a1 = row[lane + 64];
    float4 b0 = qv[lane],       b1 = qv[lane + 64];
    float d = dot4(a1, b1, dot4(a0, b0, 0.f));
    #pragma unroll
    for (int off = 32; off > 0; off >>= 1) d += __shfl_xor(d, off);
    if (lane == 0) v[r] = d;
}

// Stage 3: wave-per-row dots, masks preloaded (R7-validated body),
// fast tanh; per-block online-softmax partial. No compat array stored.
__global__ __launch_bounds__(CP_THREADS) void compat_kernel(
    const float* __restrict__ q, const int* __restrict__ mask,
    const float* __restrict__ v,
    float* __restrict__ pm, float* __restrict__ ps, int* __restrict__ pidx) {
    int t = threadIdx.x;
    int lane = t & 63;
    int w = t >> 6;
    int wid = (blockIdx.x * CP_THREADS + t) >> 6;
    const int nw = (CP_BLOCKS * CP_THREADS) >> 6;   // 8192 waves

    const float4* vv = (const float4*)v;
    float4 vb0 = vv[lane];
    float4 vb1 = vv[lane + 64];

    // preload all masks for this wave's rows (independent wave-uniform loads)
    int mk[KMAX];
    #pragma unroll
    for (int k = 0; k < KMAX; ++k) {
        int n = wid + k * nw;
        mk[k] = (n < NROWS) ? mask[n] : 0;
    }

    float m = -INFINITY, s = 0.f;
    int idx = 0x7fffffff;
    #pragma unroll
    for (int k = 0; k < KMAX; ++k) {
        int n = wid + k * nw;
        if (mk[k]) {
            const float4* row = (const float4*)(q + (size_t)n * DIM);
            float4 a0 = row[lane];
            float4 a1 = row[lane + 64];
            float d = dot4(a1, vb1, dot4(a0, vb0, 0.f));
            #pragma unroll
            for (int off = 32; off > 0; off >>= 1) d += __shfl_xor(d, off);
            float c = tanh10(NORM * d);
            sm_combine(m, s, idx, c, 1.0f, n);
        }
    }

    __shared__ float bm[CP_THREADS / 64], bs[CP_THREADS / 64];
    __shared__ int bidx[CP_THREADS / 64];
    if (lane == 0) { bm[w] = m; bs[w] = s; bidx[w] = idx; }
    __syncthreads();
    if (t == 0) {
        float M = bm[0], S = bs[0];
        int I = bidx[0];
        for (int i = 1; i < CP_THREADS / 64; ++i)
            sm_combine(M, S, I, bm[i], bs[i], bidx[i]);
        pm[blockIdx.x] = M;
        ps[blockIdx.x] = S;
        pidx[blockIdx.x] = I;
    }
}

// Stage 4: combine partials; attn/log_attn/idx; q_max copy.
// Random path recomputes its compat from q[ix].v (validated R8-R10).
__global__ __launch_bounds__(512) void finalize_kernel(
    const float* __restrict__ q, const int* __restrict__ mask,
    const float* __restrict__ v, const float* __restrict__ pm,
    const float* __restrict__ ps, const int* __restrict__ pidx,
    const int* __restrict__ is_random, const long long* __restrict__ rnet,
    float* __restrict__ out) {
    __shared__ float sm[512], ss[512], sd[512];
    __shared__ int si[512];
    int t = threadIdx.x;
    float m = -INFINITY, s = 0.f;
    int idx = 0x7fffffff;
    for (int i = t; i < CP_BLOCKS; i += 512)
        sm_combine(m, s, idx, pm[i], ps[i], pidx[i]);
    sm[t] = m; ss[t] = s; si[t] = idx;
    __syncthreads();
    for (int off = 256; off > 0; off >>= 1) {
        if (t < off) {
            float M = sm[t], S = ss[t];
            int I = si[t];
            sm_combine(M, S, I, sm[t + off], ss[t + off], si[t + off]);
            sm[t] = M; ss[t] = S; si[t] = I;
        }
        __syncthreads();
    }
    __shared__ int chosenIx, chosenRnd;
    __shared__ float chosenM, chosenS;
    if (t == 0) {
        chosenRnd = is_random[0];
        chosenIx = chosenRnd ? (int)rnet[0] : si[0];
        chosenM = sm[0];
        chosenS = ss[0];
    }
    __syncthreads();
    int ix = chosenIx;
    float r0 = q[(size_t)ix * DIM + t];
    out[t] = r0;
    sd[t] = r0 * v[t];
    __syncthreads();
    for (int off = 256; off > 0; off >>= 1) {
        if (t < off) sd[t] += sd[t + off];
        __syncthreads();
    }
    if (t == 0) {
        float Mv = chosenM, Sv = chosenS;
        float c = chosenRnd
                ? (mask[ix] ? tanh10(NORM * sd[0]) : -INFINITY)
                : Mv;                       // argmax row: compat == M exactly
        out[OUT_ATTN] = __expf(c - Mv) / Sv;
        out[OUT_LOG]  = (c - Mv) - logf(Sv);
        out[OUT_IDX]  = (float)ix;
    }
}

extern "C" void kernel_launch(void* const* d_in, const int* in_sizes, int n_in,
                              void* d_out, int out_size, void* d_ws, size_t ws_size,
                              hipStream_t stream) {
    const float*     q    = (const float*)d_in[0];
    const float*     l    = (const float*)d_in[1];
    const float*     ctx  = (const float*)d_in[2];
    const float*     g    = (const float*)d_in[3];
    const int*       mask = (const int*)d_in[4];
    const int*       isr  = (const int*)d_in[5];
    const long long* rnet = (const long long*)d_in[6];
    const float*     Wc   = (const float*)d_in[7];
    const float*     Wg   = (const float*)d_in[8];
    const float*     Wq   = (const float*)d_in[9];
    const float*     Wk   = (const float*)d_in[10];

    float* out = (float*)d_out;
    float* ws  = (float*)d_ws;
    float* qpart = ws;
    float* v     = ws + 16384;
    float* pm    = ws + 16896;
    float* ps    = ws + 18944;
    int*   pidx  = (int*)(ws + 20992);

    qpart_kernel<<<QP_BLOCKS, 256, 0, stream>>>(l, ctx, g, Wc, Wg, Wq, mask,
                                                qpart, out + 514, out + 1026);
    v_kernel<<<VK_BLOCKS, 256, 0, stream>>>(Wk, qpart, v);
    compat_kernel<<<CP_BLOCKS, CP_THREADS, 0, stream>>>(q, mask, v, pm, ps, pidx);
    finalize_kernel<<<1, 512, 0, stream>>>(q, mask, v, pm, ps, pidx,
                                           isr, rnet, out);
}